// Round 1
// baseline (584.633 us; speedup 1.0000x reference)
//
#include <hip/hip_runtime.h>

#define N_NODES   50000
#define HID       64
#define N_GRAPHS  128
#define N_CLASSES 10

// ---------------- CSR build (counting sort by dst) ----------------

__global__ void deg_kernel(const int* __restrict__ dst, int* __restrict__ deg, int E) {
    int e = blockIdx.x * blockDim.x + threadIdx.x;
    if (e < E) atomicAdd(&deg[dst[e]], 1);
}

__global__ void scan1(const int* __restrict__ deg, int* __restrict__ blocksum, int N) {
    __shared__ int sm[256];
    int t = threadIdx.x;
    int n = blockIdx.x * 256 + t;
    sm[t] = (n < N) ? deg[n] : 0;
    __syncthreads();
    for (int off = 128; off > 0; off >>= 1) {
        if (t < off) sm[t] += sm[t + off];
        __syncthreads();
    }
    if (t == 0) blocksum[blockIdx.x] = sm[0];
}

__global__ void scan2(const int* __restrict__ blocksum, int* __restrict__ blockoff, int NB) {
    __shared__ int sm[256];
    int t = threadIdx.x;
    int v = (t < NB) ? blocksum[t] : 0;
    sm[t] = v;
    __syncthreads();
    for (int off = 1; off < 256; off <<= 1) {
        int add = (t >= off) ? sm[t - off] : 0;
        __syncthreads();
        sm[t] += add;
        __syncthreads();
    }
    if (t < NB) blockoff[t] = sm[t] - v;  // exclusive scan
}

__global__ void scan3(const int* __restrict__ deg, const int* __restrict__ blockoff,
                      int* __restrict__ offsets, int* __restrict__ cursor, int N) {
    __shared__ int sm[256];
    int t = threadIdx.x;
    int n = blockIdx.x * 256 + t;
    int d = (n < N) ? deg[n] : 0;
    sm[t] = d;
    __syncthreads();
    for (int off = 1; off < 256; off <<= 1) {
        int add = (t >= off) ? sm[t - off] : 0;
        __syncthreads();
        sm[t] += add;
        __syncthreads();
    }
    int excl = sm[t] - d + blockoff[blockIdx.x];
    if (n < N) {
        offsets[n] = excl;
        cursor[n]  = excl;
        if (n == N - 1) offsets[N] = excl + d;
    }
}

__global__ void fill_kernel(const int* __restrict__ src, const int* __restrict__ dst,
                            int* __restrict__ cursor, int* __restrict__ csr_src, int E) {
    int e = blockIdx.x * blockDim.x + threadIdx.x;
    if (e < E) {
        int pos = atomicAdd(&cursor[dst[e]], 1);
        csr_src[pos] = src[e];
    }
}

// ---------------- Fused GraphConv layer ----------------
// One wave per node; lane = output channel. Aggregate incoming rows, then
// h_out = relu?(agg @ Wrel^T + b + x @ Wroot^T). Weights staged in LDS as
// transposed float4-packed [k4][o] for conflict-free ds_read_b128.

template <int RELU>
__global__ __launch_bounds__(256) void layer_kernel(
    const float* __restrict__ hin,
    const int* __restrict__ offsets, const int* __restrict__ csr_src,
    const float* __restrict__ Wrel, const float* __restrict__ bias,
    const float* __restrict__ Wroot, float* __restrict__ hout) {
    __shared__ float4 wrel4[1024];   // [k4=0..15][o=0..63] -> W[o][4k4..4k4+3]
    __shared__ float4 wroot4[1024];
    __shared__ float rowbuf[4][2][64];

    int tid = threadIdx.x;
    for (int i = tid; i < 1024; i += 256) {
        int o = i >> 4, k4 = i & 15;
        wrel4[k4 * 64 + o]  = *(const float4*)(Wrel  + o * 64 + k4 * 4);
        wroot4[k4 * 64 + o] = *(const float4*)(Wroot + o * 64 + k4 * 4);
    }

    int w = tid >> 6, lane = tid & 63;
    int n = blockIdx.x * 4 + w;       // grid = N/4 exactly
    int beg = offsets[n], end = offsets[n + 1];

    float acc0 = 0.f, acc1 = 0.f;
    for (int base = beg; base < end; base += 64) {
        int cnt = min(64, end - base);
        int me  = base + lane;
        int s   = (me < end) ? csr_src[me] : 0;   // coalesced chunk of edge srcs
        int j = 0;
        for (; j + 4 <= cnt; j += 4) {
            int s0 = __shfl(s, j);
            int s1 = __shfl(s, j + 1);
            int s2 = __shfl(s, j + 2);
            int s3 = __shfl(s, j + 3);
            float v0 = hin[s0 * 64 + lane];
            float v1 = hin[s1 * 64 + lane];
            float v2 = hin[s2 * 64 + lane];
            float v3 = hin[s3 * 64 + lane];
            acc0 += v0; acc1 += v1; acc0 += v2; acc1 += v3;
        }
        for (; j < cnt; ++j) {
            int sj = __shfl(s, j);
            acc0 += hin[sj * 64 + lane];
        }
    }
    float agg = acc0 + acc1;
    float xv  = hin[n * 64 + lane];

    rowbuf[w][0][lane] = agg;
    rowbuf[w][1][lane] = xv;
    __syncthreads();   // covers weight staging + rowbuf cross-lane reads

    float outv = bias[lane];
    const float4* arow = (const float4*)&rowbuf[w][0][0];
    const float4* xrow = (const float4*)&rowbuf[w][1][0];
#pragma unroll
    for (int k4 = 0; k4 < 16; ++k4) {
        float4 a  = arow[k4];          // broadcast (same addr across wave)
        float4 xx = xrow[k4];
        float4 wr = wrel4[k4 * 64 + lane];
        float4 wo = wroot4[k4 * 64 + lane];
        outv += wr.x * a.x + wr.y * a.y + wr.z * a.z + wr.w * a.w
              + wo.x * xx.x + wo.y * xx.y + wo.z * xx.z + wo.w * xx.w;
    }
    if (RELU) outv = fmaxf(outv, 0.f);
    hout[n * 64 + lane] = outv;
}

// ---------------- Pooling: segmented (batch is sorted) ----------------

__global__ __launch_bounds__(256) void pool_kernel(
    const float* __restrict__ h, const int* __restrict__ batch,
    float* __restrict__ sums, int* __restrict__ cnt) {
    int tid = threadIdx.x;
    int w = tid >> 6, lane = tid & 63;
    int n0 = blockIdx.x * 128 + w * 32;
    if (n0 >= N_NODES) return;
    int nend = min(n0 + 32, N_NODES);
    int cur = batch[n0];
    float acc = 0.f;
    int run = 0;
    for (int n = n0; n < nend; ++n) {
        int g = batch[n];                 // wave-uniform load
        if (g != cur) {
            atomicAdd(&sums[cur * 64 + lane], acc);
            if (lane == 0) atomicAdd(&cnt[cur], run);
            acc = 0.f; run = 0; cur = g;
        }
        acc += h[n * 64 + lane];
        run++;
    }
    atomicAdd(&sums[cur * 64 + lane], acc);
    if (lane == 0) atomicAdd(&cnt[cur], run);
}

__global__ void final_kernel(const float* __restrict__ sums, const int* __restrict__ cnt,
                             const float* __restrict__ Wlin, const float* __restrict__ blin,
                             float* __restrict__ out) {
    __shared__ float pl[64];
    int g = blockIdx.x, lane = threadIdx.x;
    float c = fmaxf((float)cnt[g], 1.0f);
    float p = sums[g * 64 + lane] / c;
    out[g * 64 + lane] = p;               // pooled output
    pl[lane] = p;
    __syncthreads();
    if (lane < N_CLASSES) {
        float o = blin[lane];
#pragma unroll
        for (int k = 0; k < 64; ++k) o += pl[k] * Wlin[lane * 64 + k];
        out[N_GRAPHS * 64 + g * N_CLASSES + lane] = o;  // classifier output
    }
}

// ---------------- Launch ----------------

extern "C" void kernel_launch(void* const* d_in, const int* in_sizes, int n_in,
                              void* d_out, int out_size, void* d_ws, size_t ws_size,
                              hipStream_t stream) {
    const float* x     = (const float*)d_in[0];
    const int*   ei    = (const int*)d_in[1];
    const int*   batch = (const int*)d_in[2];
    const float* W1r = (const float*)d_in[3];
    const float* b1  = (const float*)d_in[4];
    const float* W1o = (const float*)d_in[5];
    const float* W2r = (const float*)d_in[6];
    const float* b2  = (const float*)d_in[7];
    const float* W2o = (const float*)d_in[8];
    const float* W3r = (const float*)d_in[9];
    const float* b3  = (const float*)d_in[10];
    const float* W3o = (const float*)d_in[11];
    const float* Wl  = (const float*)d_in[12];
    const float* bl  = (const float*)d_in[13];
    float* out = (float*)d_out;

    const int E = in_sizes[1] / 2;
    const int* src = ei;
    const int* dst = ei + E;

    char* p = (char*)d_ws;
    float* h1      = (float*)p; p += (size_t)N_NODES * 64 * 4;
    float* h2      = (float*)p; p += (size_t)N_NODES * 64 * 4;
    float* h3      = (float*)p; p += (size_t)N_NODES * 64 * 4;
    int* csr_src   = (int*)p;   p += (size_t)E * 4;
    int* deg       = (int*)p;   p += (size_t)N_NODES * 4;
    int* offsets   = (int*)p;   p += (size_t)(N_NODES + 1) * 4;
    int* cursor    = (int*)p;   p += (size_t)N_NODES * 4;
    int* blocksum  = (int*)p;   p += 256 * 4;
    int* blockoff  = (int*)p;   p += 256 * 4;
    float* sums    = (float*)p; p += (size_t)N_GRAPHS * 64 * 4;
    int* cnt       = (int*)p;   p += N_GRAPHS * 4;

    hipMemsetAsync(deg, 0, (size_t)N_NODES * 4, stream);
    hipMemsetAsync(sums, 0, (size_t)(N_GRAPHS * 64 + N_GRAPHS) * 4, stream);

    const int NB = (N_NODES + 255) / 256;  // 196
    deg_kernel<<<(E + 255) / 256, 256, 0, stream>>>(dst, deg, E);
    scan1<<<NB, 256, 0, stream>>>(deg, blocksum, N_NODES);
    scan2<<<1, 256, 0, stream>>>(blocksum, blockoff, NB);
    scan3<<<NB, 256, 0, stream>>>(deg, blockoff, offsets, cursor, N_NODES);
    fill_kernel<<<(E + 255) / 256, 256, 0, stream>>>(src, dst, cursor, csr_src, E);

    layer_kernel<1><<<N_NODES / 4, 256, 0, stream>>>(x,  offsets, csr_src, W1r, b1, W1o, h1);
    layer_kernel<1><<<N_NODES / 4, 256, 0, stream>>>(h1, offsets, csr_src, W2r, b2, W2o, h2);
    layer_kernel<0><<<N_NODES / 4, 256, 0, stream>>>(h2, offsets, csr_src, W3r, b3, W3o, h3);

    pool_kernel<<<(N_NODES + 127) / 128, 256, 0, stream>>>(h3, batch, sums, cnt);
    final_kernel<<<N_GRAPHS, 64, 0, stream>>>(sums, cnt, Wl, bl, out);
}

// Round 2
// 572.457 us; speedup vs baseline: 1.0213x; 1.0213x over previous
//
#include <hip/hip_runtime.h>

#define N_NODES   50000
#define HID       64
#define N_GRAPHS  128
#define N_CLASSES 10

typedef __attribute__((ext_vector_type(8))) short short8;
typedef __attribute__((ext_vector_type(4))) float f32x4;

__device__ __forceinline__ unsigned bf16rne(float f) {
    unsigned u = __float_as_uint(f);
    return (u + 0x7fffu + ((u >> 16) & 1u)) >> 16;
}
__device__ __forceinline__ unsigned pack_bf16x2(float lo, float hi) {
    return bf16rne(lo) | (bf16rne(hi) << 16);
}

// ---------------- CSR build (counting sort by dst) ----------------

__global__ void deg_kernel(const int* __restrict__ dst, int* __restrict__ deg, int E) {
    int e = blockIdx.x * blockDim.x + threadIdx.x;
    if (e < E) atomicAdd(&deg[dst[e]], 1);
}

__global__ void scan1(const int* __restrict__ deg, int* __restrict__ blocksum, int N) {
    __shared__ int sm[256];
    int t = threadIdx.x;
    int n = blockIdx.x * 256 + t;
    sm[t] = (n < N) ? deg[n] : 0;
    __syncthreads();
    for (int off = 128; off > 0; off >>= 1) {
        if (t < off) sm[t] += sm[t + off];
        __syncthreads();
    }
    if (t == 0) blocksum[blockIdx.x] = sm[0];
}

__global__ void scan2(const int* __restrict__ blocksum, int* __restrict__ blockoff, int NB) {
    __shared__ int sm[256];
    int t = threadIdx.x;
    int v = (t < NB) ? blocksum[t] : 0;
    sm[t] = v;
    __syncthreads();
    for (int off = 1; off < 256; off <<= 1) {
        int add = (t >= off) ? sm[t - off] : 0;
        __syncthreads();
        sm[t] += add;
        __syncthreads();
    }
    if (t < NB) blockoff[t] = sm[t] - v;  // exclusive scan
}

__global__ void scan3(const int* __restrict__ deg, const int* __restrict__ blockoff,
                      int* __restrict__ offsets, int* __restrict__ cursor, int N) {
    __shared__ int sm[256];
    int t = threadIdx.x;
    int n = blockIdx.x * 256 + t;
    int d = (n < N) ? deg[n] : 0;
    sm[t] = d;
    __syncthreads();
    for (int off = 1; off < 256; off <<= 1) {
        int add = (t >= off) ? sm[t - off] : 0;
        __syncthreads();
        sm[t] += add;
        __syncthreads();
    }
    int excl = sm[t] - d + blockoff[blockIdx.x];
    if (n < N) {
        offsets[n] = excl;
        cursor[n]  = excl;
        if (n == N - 1) offsets[N] = excl + d;
    }
}

__global__ void fill_kernel(const int* __restrict__ src, const int* __restrict__ dst,
                            int* __restrict__ cursor, int* __restrict__ csr_src, int E) {
    int e = blockIdx.x * blockDim.x + threadIdx.x;
    if (e < E) {
        int pos = atomicAdd(&cursor[dst[e]], 1);
        csr_src[pos] = src[e];
    }
}

// ---------------- x -> bf16 conversion ----------------

__global__ void cvt_kernel(const float* __restrict__ x, unsigned short* __restrict__ xb, int n4) {
    int i = blockIdx.x * blockDim.x + threadIdx.x;
    if (i < n4) {
        float4 v = ((const float4*)x)[i];
        uint2 o;
        o.x = pack_bf16x2(v.x, v.y);
        o.y = pack_bf16x2(v.z, v.w);
        ((uint2*)xb)[i] = o;
    }
}

// ---------------- Fused GraphConv layer (bf16 features, MFMA epilogue) ----
// One wave = 16 nodes. Gather: dual-row 4B loads (lanes 0-31 row j, 32-63
// row j+1), fp32 accumulate, bf16 agg tile staged to LDS (stride 72 shorts,
// 2-way-free banking). Epilogue: 16 MFMA 16x16x32 bf16 with weight
// B-fragments in VGPRs, bias in acc init, LDS transpose, coalesced stores.

template <int RELU>
__global__ __launch_bounds__(256) void layer_kernel(
    const unsigned short* __restrict__ hin,
    const int* __restrict__ offsets, const int* __restrict__ csr_src,
    const float* __restrict__ Wrel, const float* __restrict__ bias,
    const float* __restrict__ Wroot, unsigned short* __restrict__ hout) {
    __shared__ unsigned short aggT[4][16][72];
    __shared__ unsigned short outT[4][16][72];

    const int tid = threadIdx.x;
    const int w = tid >> 6, lane = tid & 63;
    const int q = lane >> 4, c = lane & 15;
    const int half = lane >> 5, hl = lane & 31;

    // ---- weight B-fragments in registers: B[k][o], o = t*16+c, k = s*32+q*8+j
    short8 brel[4][2], broot[4][2];
    float biasv[4];
#pragma unroll
    for (int t = 0; t < 4; ++t) {
        int o = t * 16 + c;
        biasv[t] = bias[o];
#pragma unroll
        for (int s = 0; s < 2; ++s) {
            const float4* pr = (const float4*)(Wrel  + o * 64 + s * 32 + q * 8);
            const float4* po = (const float4*)(Wroot + o * 64 + s * 32 + q * 8);
            float4 r0 = pr[0], r1 = pr[1], z0 = po[0], z1 = po[1];
            short8 rr, zz;
            rr[0] = (short)bf16rne(r0.x); rr[1] = (short)bf16rne(r0.y);
            rr[2] = (short)bf16rne(r0.z); rr[3] = (short)bf16rne(r0.w);
            rr[4] = (short)bf16rne(r1.x); rr[5] = (short)bf16rne(r1.y);
            rr[6] = (short)bf16rne(r1.z); rr[7] = (short)bf16rne(r1.w);
            zz[0] = (short)bf16rne(z0.x); zz[1] = (short)bf16rne(z0.y);
            zz[2] = (short)bf16rne(z0.z); zz[3] = (short)bf16rne(z0.w);
            zz[4] = (short)bf16rne(z1.x); zz[5] = (short)bf16rne(z1.y);
            zz[6] = (short)bf16rne(z1.z); zz[7] = (short)bf16rne(z1.w);
            brel[t][s] = rr; broot[t][s] = zz;
        }
    }

    const int g0 = (blockIdx.x * 4 + w) * 16;

    // ---- gather: 16 nodes sequentially, 2 channels/lane, 2 rows/load
    for (int m = 0; m < 16; ++m) {
        int n = g0 + m;
        float accx = 0.f, accy = 0.f;
        int beg = 0, end = 0;
        if (n < N_NODES) { beg = offsets[n]; end = offsets[n + 1]; }
        for (int base = beg; base < end; base += 64) {
            int cnt = min(64, end - base);
            int s = 0;
            if (base + lane < end) s = csr_src[base + lane];
            int j = 0;
            for (; j + 16 <= cnt; j += 16) {
                unsigned u[8];
#pragma unroll
                for (int p = 0; p < 8; ++p) {
                    int r = __shfl(s, j + 2 * p + half);
                    u[p] = *((const unsigned*)(hin + (size_t)r * 64) + hl);
                }
#pragma unroll
                for (int p = 0; p < 8; ++p) {
                    accx += __uint_as_float(u[p] << 16);
                    accy += __uint_as_float(u[p] & 0xffff0000u);
                }
            }
            for (; j + 2 <= cnt; j += 2) {
                int r = __shfl(s, j + half);
                unsigned u = *((const unsigned*)(hin + (size_t)r * 64) + hl);
                accx += __uint_as_float(u << 16);
                accy += __uint_as_float(u & 0xffff0000u);
            }
            if (j < cnt) {
                int r = __shfl(s, j);
                unsigned u = 0;
                if (half == 0) u = *((const unsigned*)(hin + (size_t)r * 64) + hl);
                accx += __uint_as_float(u << 16);
                accy += __uint_as_float(u & 0xffff0000u);
            }
        }
        // combine the two halves (lane l and l^32 hold the same channel pair)
        float ox = accx + __shfl(accx, lane ^ 32);
        float oy = accy + __shfl(accy, lane ^ 32);
        if (half == 0)
            *((unsigned*)&aggT[w][m][0] + hl) = pack_bf16x2(ox, oy);
    }
    __syncthreads();  // agg tiles complete (cross-lane LDS hazard)

    // ---- A fragments: agg from LDS, x (root) from global
    short8 a_agg[2], a_x[2];
#pragma unroll
    for (int s = 0; s < 2; ++s)
        a_agg[s] = *(const short8*)&aggT[w][c][s * 32 + q * 8];
    int nx = min(g0 + c, N_NODES - 1);
    const unsigned short* xrow = hin + (size_t)nx * 64;
#pragma unroll
    for (int s = 0; s < 2; ++s)
        a_x[s] = *(const short8*)(xrow + s * 32 + q * 8);

    // ---- MFMA: D[16 nodes][64 out] in 4 col-tiles
    f32x4 acc4[4];
#pragma unroll
    for (int t = 0; t < 4; ++t) {
        f32x4 a0 = {biasv[t], biasv[t], biasv[t], biasv[t]};
        a0 = __builtin_amdgcn_mfma_f32_16x16x32_bf16(a_agg[0], brel[t][0], a0, 0, 0, 0);
        a0 = __builtin_amdgcn_mfma_f32_16x16x32_bf16(a_agg[1], brel[t][1], a0, 0, 0, 0);
        a0 = __builtin_amdgcn_mfma_f32_16x16x32_bf16(a_x[0],  broot[t][0], a0, 0, 0, 0);
        a0 = __builtin_amdgcn_mfma_f32_16x16x32_bf16(a_x[1],  broot[t][1], a0, 0, 0, 0);
        acc4[t] = a0;
    }

    // ---- ReLU + bf16 + LDS transpose (C/D layout: col=lane&15, row=q*4+reg)
#pragma unroll
    for (int t = 0; t < 4; ++t)
#pragma unroll
        for (int r = 0; r < 4; ++r) {
            float v = acc4[t][r];
            if (RELU) v = fmaxf(v, 0.f);
            outT[w][q * 4 + r][t * 16 + c] = (unsigned short)bf16rne(v);
        }
    __syncthreads();

    // ---- coalesced stores: 8 rows/iter, 8 lanes x 16 B per row
#pragma unroll
    for (int it = 0; it < 2; ++it) {
        int row = it * 8 + (lane >> 3);
        int ch = (lane & 7) * 8;
        int n = g0 + row;
        if (n < N_NODES) {
            short8 v = *(const short8*)&outT[w][row][ch];
            *(short8*)(hout + (size_t)n * 64 + ch) = v;
        }
    }
}

// ---------------- Pooling: segmented (batch is sorted), bf16 input -------

__global__ __launch_bounds__(256) void pool_kernel(
    const unsigned short* __restrict__ h, const int* __restrict__ batch,
    float* __restrict__ sums, int* __restrict__ cnt) {
    int tid = threadIdx.x;
    int w = tid >> 6, lane = tid & 63;
    int n0 = blockIdx.x * 128 + w * 32;
    if (n0 >= N_NODES) return;
    int nend = min(n0 + 32, N_NODES);
    int cur = batch[n0];
    float acc = 0.f;
    int run = 0;
    for (int n = n0; n < nend; ++n) {
        int g = batch[n];                 // wave-uniform load
        if (g != cur) {
            atomicAdd(&sums[cur * 64 + lane], acc);
            if (lane == 0) atomicAdd(&cnt[cur], run);
            acc = 0.f; run = 0; cur = g;
        }
        unsigned u = h[(size_t)n * 64 + lane];
        acc += __uint_as_float(u << 16);
        run++;
    }
    atomicAdd(&sums[cur * 64 + lane], acc);
    if (lane == 0) atomicAdd(&cnt[cur], run);
}

__global__ void final_kernel(const float* __restrict__ sums, const int* __restrict__ cnt,
                             const float* __restrict__ Wlin, const float* __restrict__ blin,
                             float* __restrict__ out) {
    __shared__ float pl[64];
    int g = blockIdx.x, lane = threadIdx.x;
    float cdiv = fmaxf((float)cnt[g], 1.0f);
    float p = sums[g * 64 + lane] / cdiv;
    out[g * 64 + lane] = p;               // pooled output
    pl[lane] = p;
    __syncthreads();
    if (lane < N_CLASSES) {
        float o = blin[lane];
#pragma unroll
        for (int k = 0; k < 64; ++k) o += pl[k] * Wlin[lane * 64 + k];
        out[N_GRAPHS * 64 + g * N_CLASSES + lane] = o;  // classifier output
    }
}

// ---------------- Launch ----------------

extern "C" void kernel_launch(void* const* d_in, const int* in_sizes, int n_in,
                              void* d_out, int out_size, void* d_ws, size_t ws_size,
                              hipStream_t stream) {
    const float* x     = (const float*)d_in[0];
    const int*   ei    = (const int*)d_in[1];
    const int*   batch = (const int*)d_in[2];
    const float* W1r = (const float*)d_in[3];
    const float* b1  = (const float*)d_in[4];
    const float* W1o = (const float*)d_in[5];
    const float* W2r = (const float*)d_in[6];
    const float* b2  = (const float*)d_in[7];
    const float* W2o = (const float*)d_in[8];
    const float* W3r = (const float*)d_in[9];
    const float* b3  = (const float*)d_in[10];
    const float* W3o = (const float*)d_in[11];
    const float* Wl  = (const float*)d_in[12];
    const float* bl  = (const float*)d_in[13];
    float* out = (float*)d_out;

    const int E = in_sizes[1] / 2;
    const int* src = ei;
    const int* dst = ei + E;

    char* p = (char*)d_ws;
    unsigned short* xb = (unsigned short*)p; p += (size_t)N_NODES * 64 * 2;
    unsigned short* h1 = (unsigned short*)p; p += (size_t)N_NODES * 64 * 2;
    unsigned short* h2 = (unsigned short*)p; p += (size_t)N_NODES * 64 * 2;
    unsigned short* h3 = (unsigned short*)p; p += (size_t)N_NODES * 64 * 2;
    int* csr_src   = (int*)p;   p += (size_t)E * 4;
    int* deg       = (int*)p;   p += (size_t)N_NODES * 4;
    int* offsets   = (int*)p;   p += (size_t)(N_NODES + 1) * 4;
    int* cursor    = (int*)p;   p += (size_t)N_NODES * 4;
    int* blocksum  = (int*)p;   p += 256 * 4;
    int* blockoff  = (int*)p;   p += 256 * 4;
    float* sums    = (float*)p; p += (size_t)N_GRAPHS * 64 * 4;
    int* cnt       = (int*)p;   p += N_GRAPHS * 4;

    hipMemsetAsync(deg, 0, (size_t)N_NODES * 4, stream);
    hipMemsetAsync(sums, 0, (size_t)(N_GRAPHS * 64 + N_GRAPHS) * 4, stream);

    const int NB = (N_NODES + 255) / 256;  // 196
    deg_kernel<<<(E + 255) / 256, 256, 0, stream>>>(dst, deg, E);
    cvt_kernel<<<(N_NODES * 64 / 4 + 255) / 256, 256, 0, stream>>>(x, xb, N_NODES * 64 / 4);
    scan1<<<NB, 256, 0, stream>>>(deg, blocksum, N_NODES);
    scan2<<<1, 256, 0, stream>>>(blocksum, blockoff, NB);
    scan3<<<NB, 256, 0, stream>>>(deg, blockoff, offsets, cursor, N_NODES);
    fill_kernel<<<(E + 255) / 256, 256, 0, stream>>>(src, dst, cursor, csr_src, E);

    const int LB = (N_NODES + 63) / 64;   // 782 blocks, 64 nodes each
    layer_kernel<1><<<LB, 256, 0, stream>>>(xb, offsets, csr_src, W1r, b1, W1o, h1);
    layer_kernel<1><<<LB, 256, 0, stream>>>(h1, offsets, csr_src, W2r, b2, W2o, h2);
    layer_kernel<0><<<LB, 256, 0, stream>>>(h2, offsets, csr_src, W3r, b3, W3o, h3);

    pool_kernel<<<(N_NODES + 127) / 128, 256, 0, stream>>>(h3, batch, sums, cnt);
    final_kernel<<<N_GRAPHS, 64, 0, stream>>>(sums, cnt, Wl, bl, out);
}

// Round 3
// 392.266 us; speedup vs baseline: 1.4904x; 1.4594x over previous
//
#include <hip/hip_runtime.h>

#define N_NODES   50000
#define HID       64
#define N_GRAPHS  128
#define N_CLASSES 10

typedef __attribute__((ext_vector_type(8))) short short8;
typedef __attribute__((ext_vector_type(4))) float f32x4;

__device__ __forceinline__ unsigned bf16rne(float f) {
    unsigned u = __float_as_uint(f);
    return (u + 0x7fffu + ((u >> 16) & 1u)) >> 16;
}
__device__ __forceinline__ unsigned pack_bf16x2(float lo, float hi) {
    return bf16rne(lo) | (bf16rne(hi) << 16);
}

// ---------------- CSR build (counting sort by dst) ----------------

__global__ void deg_kernel(const int* __restrict__ dst, int* __restrict__ deg, int E) {
    int e = blockIdx.x * blockDim.x + threadIdx.x;
    if (e < E) atomicAdd(&deg[dst[e]], 1);
}

__global__ void scan1(const int* __restrict__ deg, int* __restrict__ blocksum, int N) {
    __shared__ int sm[256];
    int t = threadIdx.x;
    int n = blockIdx.x * 256 + t;
    sm[t] = (n < N) ? deg[n] : 0;
    __syncthreads();
    for (int off = 128; off > 0; off >>= 1) {
        if (t < off) sm[t] += sm[t + off];
        __syncthreads();
    }
    if (t == 0) blocksum[blockIdx.x] = sm[0];
}

__global__ void scan2(const int* __restrict__ blocksum, int* __restrict__ blockoff, int NB) {
    __shared__ int sm[256];
    int t = threadIdx.x;
    int v = (t < NB) ? blocksum[t] : 0;
    sm[t] = v;
    __syncthreads();
    for (int off = 1; off < 256; off <<= 1) {
        int add = (t >= off) ? sm[t - off] : 0;
        __syncthreads();
        sm[t] += add;
        __syncthreads();
    }
    if (t < NB) blockoff[t] = sm[t] - v;  // exclusive scan
}

__global__ void scan3(const int* __restrict__ deg, const int* __restrict__ blockoff,
                      int* __restrict__ offsets, int* __restrict__ cursor, int N) {
    __shared__ int sm[256];
    int t = threadIdx.x;
    int n = blockIdx.x * 256 + t;
    int d = (n < N) ? deg[n] : 0;
    sm[t] = d;
    __syncthreads();
    for (int off = 1; off < 256; off <<= 1) {
        int add = (t >= off) ? sm[t - off] : 0;
        __syncthreads();
        sm[t] += add;
        __syncthreads();
    }
    int excl = sm[t] - d + blockoff[blockIdx.x];
    if (n < N) {
        offsets[n] = excl;
        cursor[n]  = excl;
        if (n == N - 1) offsets[N] = excl + d;
    }
}

__global__ void fill_kernel(const int* __restrict__ src, const int* __restrict__ dst,
                            int* __restrict__ cursor, int* __restrict__ csr_src, int E) {
    int e = blockIdx.x * blockDim.x + threadIdx.x;
    if (e < E) {
        int pos = atomicAdd(&cursor[dst[e]], 1);
        csr_src[pos] = src[e];
    }
}

// ---------------- x -> bf16 conversion ----------------

__global__ void cvt_kernel(const float* __restrict__ x, unsigned short* __restrict__ xb, int n4) {
    int i = blockIdx.x * blockDim.x + threadIdx.x;
    if (i < n4) {
        float4 v = ((const float4*)x)[i];
        uint2 o;
        o.x = pack_bf16x2(v.x, v.y);
        o.y = pack_bf16x2(v.z, v.w);
        ((uint2*)xb)[i] = o;
    }
}

// ---------------- Gather: one wave per node ----------------
// Dual-row 4B loads: lanes 0-31 edge e (32 dwords = 64 bf16 ch), lanes 32-63
// edge e+1. 8 loads per round, rounds independent -> deep MLP. fp32 accum,
// halves combined by shfl, 128B coalesced bf16 row store. No LDS.

__global__ __launch_bounds__(256) void gather_kernel(
    const unsigned short* __restrict__ hin,
    const int* __restrict__ offsets, const int* __restrict__ csr_src,
    unsigned short* __restrict__ agg) {
    const int w = threadIdx.x >> 6, lane = threadIdx.x & 63;
    const int half = lane >> 5, hl = lane & 31;
    const int n = blockIdx.x * 4 + w;          // grid = N/4 exactly
    const int beg = offsets[n], end = offsets[n + 1];

    float accx = 0.f, accy = 0.f;
    for (int base = beg; base < end; base += 64) {
        int cnt = min(64, end - base);
        int s = (base + lane < end) ? csr_src[base + lane] : 0;
        for (int kb = 0; kb < 64; kb += 16) {  // 16 edges (8 dual loads) per round
            if (kb >= cnt) break;
            unsigned u[8];
#pragma unroll
            for (int p = 0; p < 8; ++p) {
                int e = kb + 2 * p + half;
                int r = __shfl(s, e);
                u[p] = (e < cnt) ? *((const unsigned*)(hin + (size_t)r * 64) + hl) : 0u;
            }
#pragma unroll
            for (int p = 0; p < 8; ++p) {
                accx += __uint_as_float(u[p] << 16);
                accy += __uint_as_float(u[p] & 0xffff0000u);
            }
        }
    }
    float ox = accx + __shfl(accx, lane ^ 32);
    float oy = accy + __shfl(accy, lane ^ 32);
    if (half == 0)
        *((unsigned*)(agg + (size_t)n * 64) + hl) = pack_bf16x2(ox, oy);
}

// ---------------- Linear: streaming MFMA ----------------
// One wave = 16 nodes: hout = relu?(agg@Wrel^T + b + hin@Wroot^T).
// Weights as VGPR B-fragments, bias folded into acc init, A-fragments read
// straight from global rows, LDS only for per-wave output transpose (no
// barriers - each wave touches only outT[w]).

template <int RELU>
__global__ __launch_bounds__(256) void linear_kernel(
    const unsigned short* __restrict__ agg,
    const unsigned short* __restrict__ hin,
    const float* __restrict__ Wrel, const float* __restrict__ bias,
    const float* __restrict__ Wroot, unsigned short* __restrict__ hout) {
    __shared__ unsigned short outT[4][16][72];

    const int tid = threadIdx.x;
    const int w = tid >> 6, lane = tid & 63;
    const int q = lane >> 4, c = lane & 15;
    const int g0 = (blockIdx.x * 4 + w) * 16;
    if (g0 >= N_NODES) return;

    // weight B-fragments: B[k][o], o = t*16+c, k = s*32+q*8+j
    short8 brel[4][2], broot[4][2];
    float biasv[4];
#pragma unroll
    for (int t = 0; t < 4; ++t) {
        int o = t * 16 + c;
        biasv[t] = bias[o];
#pragma unroll
        for (int s = 0; s < 2; ++s) {
            const float4* pr = (const float4*)(Wrel  + o * 64 + s * 32 + q * 8);
            const float4* po = (const float4*)(Wroot + o * 64 + s * 32 + q * 8);
            float4 r0 = pr[0], r1 = pr[1], z0 = po[0], z1 = po[1];
            short8 rr, zz;
            rr[0] = (short)bf16rne(r0.x); rr[1] = (short)bf16rne(r0.y);
            rr[2] = (short)bf16rne(r0.z); rr[3] = (short)bf16rne(r0.w);
            rr[4] = (short)bf16rne(r1.x); rr[5] = (short)bf16rne(r1.y);
            rr[6] = (short)bf16rne(r1.z); rr[7] = (short)bf16rne(r1.w);
            zz[0] = (short)bf16rne(z0.x); zz[1] = (short)bf16rne(z0.y);
            zz[2] = (short)bf16rne(z0.z); zz[3] = (short)bf16rne(z0.w);
            zz[4] = (short)bf16rne(z1.x); zz[5] = (short)bf16rne(z1.y);
            zz[6] = (short)bf16rne(z1.z); zz[7] = (short)bf16rne(z1.w);
            brel[t][s] = rr; broot[t][s] = zz;
        }
    }

    // A fragments straight from global: A[m=c][k=s*32+q*8+j]
    const int na = min(g0 + c, N_NODES - 1);
    short8 a_agg[2], a_x[2];
#pragma unroll
    for (int s = 0; s < 2; ++s) {
        a_agg[s] = *(const short8*)(agg + (size_t)na * 64 + s * 32 + q * 8);
        a_x[s]   = *(const short8*)(hin + (size_t)na * 64 + s * 32 + q * 8);
    }

    f32x4 acc4[4];
#pragma unroll
    for (int t = 0; t < 4; ++t) {
        f32x4 a0 = {biasv[t], biasv[t], biasv[t], biasv[t]};
        a0 = __builtin_amdgcn_mfma_f32_16x16x32_bf16(a_agg[0], brel[t][0], a0, 0, 0, 0);
        a0 = __builtin_amdgcn_mfma_f32_16x16x32_bf16(a_agg[1], brel[t][1], a0, 0, 0, 0);
        a0 = __builtin_amdgcn_mfma_f32_16x16x32_bf16(a_x[0],  broot[t][0], a0, 0, 0, 0);
        a0 = __builtin_amdgcn_mfma_f32_16x16x32_bf16(a_x[1],  broot[t][1], a0, 0, 0, 0);
        acc4[t] = a0;
    }

    // ReLU + bf16 + per-wave LDS transpose (C/D: col=lane&15, row=q*4+reg)
#pragma unroll
    for (int t = 0; t < 4; ++t)
#pragma unroll
        for (int r = 0; r < 4; ++r) {
            float v = acc4[t][r];
            if (RELU) v = fmaxf(v, 0.f);
            outT[w][q * 4 + r][t * 16 + c] = (unsigned short)bf16rne(v);
        }
    // same-wave LDS RAW: compiler emits lgkmcnt wait; no barrier needed

#pragma unroll
    for (int it = 0; it < 2; ++it) {
        int row = it * 8 + (lane >> 3);
        int ch = (lane & 7) * 8;
        int n = g0 + row;
        if (n < N_NODES) {
            short8 v = *(const short8*)&outT[w][row][ch];
            *(short8*)(hout + (size_t)n * 64 + ch) = v;
        }
    }
}

// ---------------- Pooling: segmented (batch is sorted), bf16 input -------

__global__ __launch_bounds__(256) void pool_kernel(
    const unsigned short* __restrict__ h, const int* __restrict__ batch,
    float* __restrict__ sums, int* __restrict__ cnt) {
    int tid = threadIdx.x;
    int w = tid >> 6, lane = tid & 63;
    int n0 = blockIdx.x * 128 + w * 32;
    if (n0 >= N_NODES) return;
    int nend = min(n0 + 32, N_NODES);
    int cur = batch[n0];
    float acc = 0.f;
    int run = 0;
    for (int n = n0; n < nend; ++n) {
        int g = batch[n];                 // wave-uniform load
        if (g != cur) {
            atomicAdd(&sums[cur * 64 + lane], acc);
            if (lane == 0) atomicAdd(&cnt[cur], run);
            acc = 0.f; run = 0; cur = g;
        }
        unsigned u = h[(size_t)n * 64 + lane];
        acc += __uint_as_float(u << 16);
        run++;
    }
    atomicAdd(&sums[cur * 64 + lane], acc);
    if (lane == 0) atomicAdd(&cnt[cur], run);
}

__global__ void final_kernel(const float* __restrict__ sums, const int* __restrict__ cnt,
                             const float* __restrict__ Wlin, const float* __restrict__ blin,
                             float* __restrict__ out) {
    __shared__ float pl[64];
    int g = blockIdx.x, lane = threadIdx.x;
    float cdiv = fmaxf((float)cnt[g], 1.0f);
    float p = sums[g * 64 + lane] / cdiv;
    out[g * 64 + lane] = p;               // pooled output
    pl[lane] = p;
    __syncthreads();
    if (lane < N_CLASSES) {
        float o = blin[lane];
#pragma unroll
        for (int k = 0; k < 64; ++k) o += pl[k] * Wlin[lane * 64 + k];
        out[N_GRAPHS * 64 + g * N_CLASSES + lane] = o;  // classifier output
    }
}

// ---------------- Launch ----------------

extern "C" void kernel_launch(void* const* d_in, const int* in_sizes, int n_in,
                              void* d_out, int out_size, void* d_ws, size_t ws_size,
                              hipStream_t stream) {
    const float* x     = (const float*)d_in[0];
    const int*   ei    = (const int*)d_in[1];
    const int*   batch = (const int*)d_in[2];
    const float* W1r = (const float*)d_in[3];
    const float* b1  = (const float*)d_in[4];
    const float* W1o = (const float*)d_in[5];
    const float* W2r = (const float*)d_in[6];
    const float* b2  = (const float*)d_in[7];
    const float* W2o = (const float*)d_in[8];
    const float* W3r = (const float*)d_in[9];
    const float* b3  = (const float*)d_in[10];
    const float* W3o = (const float*)d_in[11];
    const float* Wl  = (const float*)d_in[12];
    const float* bl  = (const float*)d_in[13];
    float* out = (float*)d_out;

    const int E = in_sizes[1] / 2;
    const int* src = ei;
    const int* dst = ei + E;

    char* p = (char*)d_ws;
    unsigned short* xb  = (unsigned short*)p; p += (size_t)N_NODES * 64 * 2;
    unsigned short* h1  = (unsigned short*)p; p += (size_t)N_NODES * 64 * 2;
    unsigned short* h2  = (unsigned short*)p; p += (size_t)N_NODES * 64 * 2;
    unsigned short* h3  = (unsigned short*)p; p += (size_t)N_NODES * 64 * 2;
    unsigned short* agg = (unsigned short*)p; p += (size_t)N_NODES * 64 * 2;
    int* csr_src   = (int*)p;   p += (size_t)E * 4;
    int* deg       = (int*)p;   p += (size_t)N_NODES * 4;
    int* offsets   = (int*)p;   p += (size_t)(N_NODES + 1) * 4;
    int* cursor    = (int*)p;   p += (size_t)N_NODES * 4;
    int* blocksum  = (int*)p;   p += 256 * 4;
    int* blockoff  = (int*)p;   p += 256 * 4;
    float* sums    = (float*)p; p += (size_t)N_GRAPHS * 64 * 4;
    int* cnt       = (int*)p;   p += N_GRAPHS * 4;

    hipMemsetAsync(deg, 0, (size_t)N_NODES * 4, stream);
    hipMemsetAsync(sums, 0, (size_t)(N_GRAPHS * 64 + N_GRAPHS) * 4, stream);

    const int NB = (N_NODES + 255) / 256;  // 196
    deg_kernel<<<(E + 255) / 256, 256, 0, stream>>>(dst, deg, E);
    cvt_kernel<<<(N_NODES * 64 / 4 + 255) / 256, 256, 0, stream>>>(x, xb, N_NODES * 64 / 4);
    scan1<<<NB, 256, 0, stream>>>(deg, blocksum, N_NODES);
    scan2<<<1, 256, 0, stream>>>(blocksum, blockoff, NB);
    scan3<<<NB, 256, 0, stream>>>(deg, blockoff, offsets, cursor, N_NODES);
    fill_kernel<<<(E + 255) / 256, 256, 0, stream>>>(src, dst, cursor, csr_src, E);

    const int GB = N_NODES / 4;            // 12500 blocks, 1 wave per node
    const int LB = (N_NODES + 63) / 64;    // 782 blocks
    gather_kernel<<<GB, 256, 0, stream>>>(xb, offsets, csr_src, agg);
    linear_kernel<1><<<LB, 256, 0, stream>>>(agg, xb, W1r, b1, W1o, h1);
    gather_kernel<<<GB, 256, 0, stream>>>(h1, offsets, csr_src, agg);
    linear_kernel<1><<<LB, 256, 0, stream>>>(agg, h1, W2r, b2, W2o, h2);
    gather_kernel<<<GB, 256, 0, stream>>>(h2, offsets, csr_src, agg);
    linear_kernel<0><<<LB, 256, 0, stream>>>(agg, h2, W3r, b3, W3o, h3);

    pool_kernel<<<(N_NODES + 127) / 128, 256, 0, stream>>>(h3, batch, sums, cnt);
    final_kernel<<<N_GRAPHS, 64, 0, stream>>>(sums, cnt, Wl, bl, out);
}

// Round 4
// 371.623 us; speedup vs baseline: 1.5732x; 1.0555x over previous
//
#include <hip/hip_runtime.h>

#define N_NODES   50000
#define HID       64
#define N_GRAPHS  128
#define N_CLASSES 10
#define NPART     8
#define PART      6250          // N_NODES / NPART
#define EPB       4096          // edges per chunk in partitioned edge kernels

typedef __attribute__((ext_vector_type(8))) short short8;
typedef __attribute__((ext_vector_type(4))) float f32x4;

__device__ __forceinline__ unsigned bf16rne(float f) {
    unsigned u = __float_as_uint(f);
    return (u + 0x7fffu + ((u >> 16) & 1u)) >> 16;
}
__device__ __forceinline__ unsigned pack_bf16x2(float lo, float hi) {
    return bf16rne(lo) | (bf16rne(hi) << 16);
}

// ---------------- CSR build (counting sort by dst) ----------------
// deg/fill are XCD-partitioned: block b handles edge chunk b>>3, partition
// b&7 (dst in [p*PART,(p+1)*PART)). Under round-robin block->XCD dispatch
// each csr/deg line is written by ONE XCD -> dirty lines coalesce in that
// XCD's L2 and write back once (was: 82 MB HBM writeback for 5 MB of data).

__global__ __launch_bounds__(256) void deg_kernel(const int* __restrict__ dst,
                                                  int* __restrict__ deg, int E) {
    const int p = blockIdx.x & (NPART - 1);
    const int chunk = blockIdx.x >> 3;
    const int lo = p * PART, hi = lo + PART;
    const int base = chunk * EPB;
    const int end = min(base + EPB, E);
    for (int e = base + threadIdx.x; e < end; e += 256) {
        int d = dst[e];
        if (d >= lo && d < hi) atomicAdd(&deg[d], 1);
    }
}

__global__ void scan1(const int* __restrict__ deg, int* __restrict__ blocksum, int N) {
    __shared__ int sm[256];
    int t = threadIdx.x;
    int n = blockIdx.x * 256 + t;
    sm[t] = (n < N) ? deg[n] : 0;
    __syncthreads();
    for (int off = 128; off > 0; off >>= 1) {
        if (t < off) sm[t] += sm[t + off];
        __syncthreads();
    }
    if (t == 0) blocksum[blockIdx.x] = sm[0];
}

__global__ void scan2(const int* __restrict__ blocksum, int* __restrict__ blockoff, int NB) {
    __shared__ int sm[256];
    int t = threadIdx.x;
    int v = (t < NB) ? blocksum[t] : 0;
    sm[t] = v;
    __syncthreads();
    for (int off = 1; off < 256; off <<= 1) {
        int add = (t >= off) ? sm[t - off] : 0;
        __syncthreads();
        sm[t] += add;
        __syncthreads();
    }
    if (t < NB) blockoff[t] = sm[t] - v;  // exclusive scan
}

__global__ void scan3(const int* __restrict__ deg, const int* __restrict__ blockoff,
                      int* __restrict__ offsets, int* __restrict__ cursor, int N) {
    __shared__ int sm[256];
    int t = threadIdx.x;
    int n = blockIdx.x * 256 + t;
    int d = (n < N) ? deg[n] : 0;
    sm[t] = d;
    __syncthreads();
    for (int off = 1; off < 256; off <<= 1) {
        int add = (t >= off) ? sm[t - off] : 0;
        __syncthreads();
        sm[t] += add;
        __syncthreads();
    }
    int excl = sm[t] - d + blockoff[blockIdx.x];
    if (n < N) {
        offsets[n] = excl;
        cursor[n]  = excl;
        if (n == N - 1) offsets[N] = excl + d;
    }
}

__global__ __launch_bounds__(256) void fill_kernel(
    const int* __restrict__ src, const int* __restrict__ dst,
    int* __restrict__ cursor, int* __restrict__ csr_src, int E) {
    const int p = blockIdx.x & (NPART - 1);
    const int chunk = blockIdx.x >> 3;
    const int lo = p * PART, hi = lo + PART;
    const int base = chunk * EPB;
    const int end = min(base + EPB, E);
    for (int e = base + threadIdx.x; e < end; e += 256) {
        int d = dst[e];
        if (d >= lo && d < hi) {
            int pos = atomicAdd(&cursor[d], 1);
            csr_src[pos] = src[e];
        }
    }
}

// ---------------- x -> bf16 conversion ----------------

__global__ void cvt_kernel(const float* __restrict__ x, unsigned short* __restrict__ xb, int n4) {
    int i = blockIdx.x * blockDim.x + threadIdx.x;
    if (i < n4) {
        float4 v = ((const float4*)x)[i];
        uint2 o;
        o.x = pack_bf16x2(v.x, v.y);
        o.y = pack_bf16x2(v.z, v.w);
        ((uint2*)xb)[i] = o;
    }
}

// ---------------- Gather: one wave per node ----------------
// Dual-row 4B loads: lanes 0-31 edge e (32 dwords = 64 bf16 ch), lanes 32-63
// edge e+1. 8 loads per round, rounds independent -> deep MLP. fp32 accum,
// halves combined by shfl, 128B coalesced bf16 row store. No LDS.

__global__ __launch_bounds__(256) void gather_kernel(
    const unsigned short* __restrict__ hin,
    const int* __restrict__ offsets, const int* __restrict__ csr_src,
    unsigned short* __restrict__ agg) {
    const int w = threadIdx.x >> 6, lane = threadIdx.x & 63;
    const int half = lane >> 5, hl = lane & 31;
    const int n = blockIdx.x * 4 + w;          // grid = N/4 exactly
    const int beg = offsets[n], end = offsets[n + 1];

    float accx = 0.f, accy = 0.f;
    for (int base = beg; base < end; base += 64) {
        int cnt = min(64, end - base);
        int s = (base + lane < end) ? csr_src[base + lane] : 0;
        for (int kb = 0; kb < 64; kb += 16) {  // 16 edges (8 dual loads) per round
            if (kb >= cnt) break;
            unsigned u[8];
#pragma unroll
            for (int p = 0; p < 8; ++p) {
                int e = kb + 2 * p + half;
                int r = __shfl(s, e);
                u[p] = (e < cnt) ? *((const unsigned*)(hin + (size_t)r * 64) + hl) : 0u;
            }
#pragma unroll
            for (int p = 0; p < 8; ++p) {
                accx += __uint_as_float(u[p] << 16);
                accy += __uint_as_float(u[p] & 0xffff0000u);
            }
        }
    }
    float ox = accx + __shfl(accx, lane ^ 32);
    float oy = accy + __shfl(accy, lane ^ 32);
    if (half == 0)
        *((unsigned*)(agg + (size_t)n * 64) + hl) = pack_bf16x2(ox, oy);
}

// ---------------- Linear: streaming MFMA ----------------
// One wave = 16 nodes: hout = relu?(agg@Wrel^T + b + hin@Wroot^T).
// Weights as VGPR B-fragments, bias folded into acc init, A-fragments read
// straight from global rows, LDS only for per-wave output transpose (no
// barriers - each wave touches only outT[w]).

template <int RELU>
__global__ __launch_bounds__(256) void linear_kernel(
    const unsigned short* __restrict__ agg,
    const unsigned short* __restrict__ hin,
    const float* __restrict__ Wrel, const float* __restrict__ bias,
    const float* __restrict__ Wroot, unsigned short* __restrict__ hout) {
    __shared__ unsigned short outT[4][16][72];

    const int tid = threadIdx.x;
    const int w = tid >> 6, lane = tid & 63;
    const int q = lane >> 4, c = lane & 15;
    const int g0 = (blockIdx.x * 4 + w) * 16;
    if (g0 >= N_NODES) return;

    // weight B-fragments: B[k][o], o = t*16+c, k = s*32+q*8+j
    short8 brel[4][2], broot[4][2];
    float biasv[4];
#pragma unroll
    for (int t = 0; t < 4; ++t) {
        int o = t * 16 + c;
        biasv[t] = bias[o];
#pragma unroll
        for (int s = 0; s < 2; ++s) {
            const float4* pr = (const float4*)(Wrel  + o * 64 + s * 32 + q * 8);
            const float4* po = (const float4*)(Wroot + o * 64 + s * 32 + q * 8);
            float4 r0 = pr[0], r1 = pr[1], z0 = po[0], z1 = po[1];
            short8 rr, zz;
            rr[0] = (short)bf16rne(r0.x); rr[1] = (short)bf16rne(r0.y);
            rr[2] = (short)bf16rne(r0.z); rr[3] = (short)bf16rne(r0.w);
            rr[4] = (short)bf16rne(r1.x); rr[5] = (short)bf16rne(r1.y);
            rr[6] = (short)bf16rne(r1.z); rr[7] = (short)bf16rne(r1.w);
            zz[0] = (short)bf16rne(z0.x); zz[1] = (short)bf16rne(z0.y);
            zz[2] = (short)bf16rne(z0.z); zz[3] = (short)bf16rne(z0.w);
            zz[4] = (short)bf16rne(z1.x); zz[5] = (short)bf16rne(z1.y);
            zz[6] = (short)bf16rne(z1.z); zz[7] = (short)bf16rne(z1.w);
            brel[t][s] = rr; broot[t][s] = zz;
        }
    }

    // A fragments straight from global: A[m=c][k=s*32+q*8+j]
    const int na = min(g0 + c, N_NODES - 1);
    short8 a_agg[2], a_x[2];
#pragma unroll
    for (int s = 0; s < 2; ++s) {
        a_agg[s] = *(const short8*)(agg + (size_t)na * 64 + s * 32 + q * 8);
        a_x[s]   = *(const short8*)(hin + (size_t)na * 64 + s * 32 + q * 8);
    }

    f32x4 acc4[4];
#pragma unroll
    for (int t = 0; t < 4; ++t) {
        f32x4 a0 = {biasv[t], biasv[t], biasv[t], biasv[t]};
        a0 = __builtin_amdgcn_mfma_f32_16x16x32_bf16(a_agg[0], brel[t][0], a0, 0, 0, 0);
        a0 = __builtin_amdgcn_mfma_f32_16x16x32_bf16(a_agg[1], brel[t][1], a0, 0, 0, 0);
        a0 = __builtin_amdgcn_mfma_f32_16x16x32_bf16(a_x[0],  broot[t][0], a0, 0, 0, 0);
        a0 = __builtin_amdgcn_mfma_f32_16x16x32_bf16(a_x[1],  broot[t][1], a0, 0, 0, 0);
        acc4[t] = a0;
    }

    // ReLU + bf16 + per-wave LDS transpose (C/D: col=lane&15, row=q*4+reg)
#pragma unroll
    for (int t = 0; t < 4; ++t)
#pragma unroll
        for (int r = 0; r < 4; ++r) {
            float v = acc4[t][r];
            if (RELU) v = fmaxf(v, 0.f);
            outT[w][q * 4 + r][t * 16 + c] = (unsigned short)bf16rne(v);
        }
    // same-wave LDS RAW: compiler emits lgkmcnt wait; no barrier needed

#pragma unroll
    for (int it = 0; it < 2; ++it) {
        int row = it * 8 + (lane >> 3);
        int ch = (lane & 7) * 8;
        int n = g0 + row;
        if (n < N_NODES) {
            short8 v = *(const short8*)&outT[w][row][ch];
            *(short8*)(hout + (size_t)n * 64 + ch) = v;
        }
    }
}

// ---------------- Pooling: segmented (batch is sorted), bf16 input -------

__global__ __launch_bounds__(256) void pool_kernel(
    const unsigned short* __restrict__ h, const int* __restrict__ batch,
    float* __restrict__ sums, int* __restrict__ cnt) {
    int tid = threadIdx.x;
    int w = tid >> 6, lane = tid & 63;
    int n0 = blockIdx.x * 128 + w * 32;
    if (n0 >= N_NODES) return;
    int nend = min(n0 + 32, N_NODES);
    int cur = batch[n0];
    float acc = 0.f;
    int run = 0;
    for (int n = n0; n < nend; ++n) {
        int g = batch[n];                 // wave-uniform load
        if (g != cur) {
            atomicAdd(&sums[cur * 64 + lane], acc);
            if (lane == 0) atomicAdd(&cnt[cur], run);
            acc = 0.f; run = 0; cur = g;
        }
        unsigned u = h[(size_t)n * 64 + lane];
        acc += __uint_as_float(u << 16);
        run++;
    }
    atomicAdd(&sums[cur * 64 + lane], acc);
    if (lane == 0) atomicAdd(&cnt[cur], run);
}

__global__ void final_kernel(const float* __restrict__ sums, const int* __restrict__ cnt,
                             const float* __restrict__ Wlin, const float* __restrict__ blin,
                             float* __restrict__ out) {
    __shared__ float pl[64];
    int g = blockIdx.x, lane = threadIdx.x;
    float cdiv = fmaxf((float)cnt[g], 1.0f);
    float p = sums[g * 64 + lane] / cdiv;
    out[g * 64 + lane] = p;               // pooled output
    pl[lane] = p;
    __syncthreads();
    if (lane < N_CLASSES) {
        float o = blin[lane];
#pragma unroll
        for (int k = 0; k < 64; ++k) o += pl[k] * Wlin[lane * 64 + k];
        out[N_GRAPHS * 64 + g * N_CLASSES + lane] = o;  // classifier output
    }
}

// ---------------- Launch ----------------

extern "C" void kernel_launch(void* const* d_in, const int* in_sizes, int n_in,
                              void* d_out, int out_size, void* d_ws, size_t ws_size,
                              hipStream_t stream) {
    const float* x     = (const float*)d_in[0];
    const int*   ei    = (const int*)d_in[1];
    const int*   batch = (const int*)d_in[2];
    const float* W1r = (const float*)d_in[3];
    const float* b1  = (const float*)d_in[4];
    const float* W1o = (const float*)d_in[5];
    const float* W2r = (const float*)d_in[6];
    const float* b2  = (const float*)d_in[7];
    const float* W2o = (const float*)d_in[8];
    const float* W3r = (const float*)d_in[9];
    const float* b3  = (const float*)d_in[10];
    const float* W3o = (const float*)d_in[11];
    const float* Wl  = (const float*)d_in[12];
    const float* bl  = (const float*)d_in[13];
    float* out = (float*)d_out;

    const int E = in_sizes[1] / 2;
    const int* src = ei;
    const int* dst = ei + E;

    char* p = (char*)d_ws;
    unsigned short* xb  = (unsigned short*)p; p += (size_t)N_NODES * 64 * 2;
    unsigned short* h1  = (unsigned short*)p; p += (size_t)N_NODES * 64 * 2;
    unsigned short* h2  = (unsigned short*)p; p += (size_t)N_NODES * 64 * 2;
    unsigned short* h3  = (unsigned short*)p; p += (size_t)N_NODES * 64 * 2;
    unsigned short* agg = (unsigned short*)p; p += (size_t)N_NODES * 64 * 2;
    int* csr_src   = (int*)p;   p += (size_t)E * 4;
    int* deg       = (int*)p;   p += (size_t)N_NODES * 4;
    int* offsets   = (int*)p;   p += (size_t)(N_NODES + 1) * 4;
    int* cursor    = (int*)p;   p += (size_t)N_NODES * 4;
    int* blocksum  = (int*)p;   p += 256 * 4;
    int* blockoff  = (int*)p;   p += 256 * 4;
    float* sums    = (float*)p; p += (size_t)N_GRAPHS * 64 * 4;
    int* cnt       = (int*)p;   p += N_GRAPHS * 4;

    hipMemsetAsync(deg, 0, (size_t)N_NODES * 4, stream);
    hipMemsetAsync(sums, 0, (size_t)(N_GRAPHS * 64 + N_GRAPHS) * 4, stream);

    const int NB = (N_NODES + 255) / 256;    // 196
    const int NCHUNK = (E + EPB - 1) / EPB;  // 306
    deg_kernel<<<NCHUNK * NPART, 256, 0, stream>>>(dst, deg, E);
    cvt_kernel<<<(N_NODES * 64 / 4 + 255) / 256, 256, 0, stream>>>(x, xb, N_NODES * 64 / 4);
    scan1<<<NB, 256, 0, stream>>>(deg, blocksum, N_NODES);
    scan2<<<1, 256, 0, stream>>>(blocksum, blockoff, NB);
    scan3<<<NB, 256, 0, stream>>>(deg, blockoff, offsets, cursor, N_NODES);
    fill_kernel<<<NCHUNK * NPART, 256, 0, stream>>>(src, dst, cursor, csr_src, E);

    const int GB = N_NODES / 4;            // 12500 blocks, 1 wave per node
    const int LB = (N_NODES + 63) / 64;    // 782 blocks
    gather_kernel<<<GB, 256, 0, stream>>>(xb, offsets, csr_src, agg);
    linear_kernel<1><<<LB, 256, 0, stream>>>(agg, xb, W1r, b1, W1o, h1);
    gather_kernel<<<GB, 256, 0, stream>>>(h1, offsets, csr_src, agg);
    linear_kernel<1><<<LB, 256, 0, stream>>>(agg, h1, W2r, b2, W2o, h2);
    gather_kernel<<<GB, 256, 0, stream>>>(h2, offsets, csr_src, agg);
    linear_kernel<0><<<LB, 256, 0, stream>>>(agg, h2, W3r, b3, W3o, h3);

    pool_kernel<<<(N_NODES + 127) / 128, 256, 0, stream>>>(h3, batch, sums, cnt);
    final_kernel<<<N_GRAPHS, 64, 0, stream>>>(sums, cnt, Wl, bl, out);
}

// Round 6
// 284.708 us; speedup vs baseline: 2.0535x; 1.3053x over previous
//
#include <hip/hip_runtime.h>

#define N_NODES   50000
#define HID       64
#define N_GRAPHS  128
#define N_CLASSES 10
#define NP        196           // partitions of 256 nodes (196*256 = 50176)
#define EPA       8192          // edges per bucket block
#define PCAP      8192          // per-partition capacity in packed[] (>20 sigma)

typedef __attribute__((ext_vector_type(8))) short short8;
typedef __attribute__((ext_vector_type(4))) float f32x4;

__device__ __forceinline__ unsigned bf16rne(float f) {
    unsigned u = __float_as_uint(f);
    return (u + 0x7fffu + ((u >> 16) & 1u)) >> 16;
}
__device__ __forceinline__ unsigned pack_bf16x2(float lo, float hi) {
    return bf16rne(lo) | (bf16rne(hi) << 16);
}

// ---------------- CSR build: 2-level LDS-staged counting sort -------------
// All global writes coalesced by construction: random scatter happens in LDS
// only. packed[] is STRIDED per partition (p*PCAP base) so the zero-based
// per-partition cursors in gcursor allocate disjoint ranges — the flat
// layout in round 5 made all partitions overlap at offset 0 (the bug).

// Pass A: bucket edges by partition p = dst>>8. Packed record:
// src (bits 0-15) | dstLocal (bits 16-23); p rides in bits 24-31 in staging.
__global__ __launch_bounds__(256) void bucket_kernel(
    const int* __restrict__ src, const int* __restrict__ dst,
    int* __restrict__ gcursor, unsigned* __restrict__ packed, int E) {
    __shared__ int hist[NP], scp[NP], base[NP], cnt2[NP];
    __shared__ int sc[256];
    __shared__ unsigned stag[EPA];
    const int t = threadIdx.x;
    const int e0 = blockIdx.x * EPA;
    const int e1 = min(e0 + EPA, E);
    for (int i = t; i < NP; i += 256) { hist[i] = 0; cnt2[i] = 0; }
    __syncthreads();
    for (int e = e0 + t; e < e1; e += 256)
        atomicAdd(&hist[dst[e] >> 8], 1);
    __syncthreads();
    sc[t] = (t < NP) ? hist[t] : 0;
    __syncthreads();
    for (int off = 1; off < 256; off <<= 1) {
        int add = (t >= off) ? sc[t - off] : 0;
        __syncthreads();
        sc[t] += add;
        __syncthreads();
    }
    if (t < NP) {
        scp[t] = sc[t] - hist[t];               // block-local exclusive scan
        if (hist[t] > 0) base[t] = atomicAdd(&gcursor[t], hist[t]);
    }
    __syncthreads();
    for (int e = e0 + t; e < e1; e += 256) {
        int d = dst[e], s = src[e];             // L2-hot re-read
        int p = d >> 8;
        int idx = scp[p] + atomicAdd(&cnt2[p], 1);
        stag[idx] = (unsigned)s | ((unsigned)(d & 255) << 16) | ((unsigned)p << 24);
    }
    __syncthreads();
    const int n = e1 - e0;
    for (int i = t; i < n; i += 256) {          // partition-contiguous runs
        unsigned v = stag[i];
        int p = v >> 24;
        packed[(size_t)p * PCAP + base[p] + (i - scp[p])] = v & 0x00FFFFFFu;
    }
}

// Tiny scan of the 196 partition counts -> csr base per partition.
__global__ void pscan_kernel(const int* __restrict__ gcursor,
                             int* __restrict__ pbase, int* __restrict__ offsets) {
    __shared__ int sc[256], v0[256];
    int t = threadIdx.x;
    int v = (t < NP) ? gcursor[t] : 0;
    sc[t] = v; v0[t] = v;
    __syncthreads();
    for (int off = 1; off < 256; off <<= 1) {
        int add = (t >= off) ? sc[t - off] : 0;
        __syncthreads();
        sc[t] += add;
        __syncthreads();
    }
    if (t < NP) pbase[t] = sc[t] - v0[t];
    if (t == 255) { pbase[NP] = sc[255]; offsets[N_NODES] = sc[255]; }
}

// Pass B: one block per partition. Local histogram+scan -> node offsets,
// scatter src into LDS csr tile, coalesced copy out. csr is ushort.
__global__ __launch_bounds__(256) void build_kernel(
    const unsigned* __restrict__ packed, const int* __restrict__ pbase,
    int* __restrict__ offsets, unsigned short* __restrict__ csr) {
    __shared__ int hist[256], lofs[256], cnt[256], sc[256];
    __shared__ unsigned short lcsr[PCAP];   // avg 6400 edges/partition, max ~6700
    const int p = blockIdx.x, t = threadIdx.x;
    const int pb = pbase[p], ne = pbase[p + 1] - pb;
    const unsigned* mypk = packed + (size_t)p * PCAP;
    hist[t] = 0; cnt[t] = 0;
    __syncthreads();
    for (int i = t; i < ne; i += 256)
        atomicAdd(&hist[(mypk[i] >> 16) & 255], 1);
    __syncthreads();
    sc[t] = hist[t];
    __syncthreads();
    for (int off = 1; off < 256; off <<= 1) {
        int add = (t >= off) ? sc[t - off] : 0;
        __syncthreads();
        sc[t] += add;
        __syncthreads();
    }
    lofs[t] = sc[t] - hist[t];
    int node = p * 256 + t;
    if (node < N_NODES) offsets[node] = pb + lofs[t];
    __syncthreads();
    for (int i = t; i < ne; i += 256) {
        unsigned v = mypk[i];
        int dl = (v >> 16) & 255;
        int slot = lofs[dl] + atomicAdd(&cnt[dl], 1);
        lcsr[slot] = (unsigned short)(v & 0xFFFFu);
    }
    __syncthreads();
    for (int i = t; i < ne; i += 256) csr[pb + i] = lcsr[i];
}

// ---------------- x -> bf16 conversion ----------------

__global__ void cvt_kernel(const float* __restrict__ x, unsigned short* __restrict__ xb, int n4) {
    int i = blockIdx.x * blockDim.x + threadIdx.x;
    if (i < n4) {
        float4 v = ((const float4*)x)[i];
        uint2 o;
        o.x = pack_bf16x2(v.x, v.y);
        o.y = pack_bf16x2(v.z, v.w);
        ((uint2*)xb)[i] = o;
    }
}

// ---------------- Gather: one wave per node ----------------
// Dual-row 4B loads: lanes 0-31 edge e (32 dwords = 64 bf16 ch), lanes 32-63
// edge e+1. 8 loads per round, rounds independent -> deep MLP. fp32 accum,
// halves combined by shfl, 128B coalesced bf16 row store. No LDS.

__global__ __launch_bounds__(256) void gather_kernel(
    const unsigned short* __restrict__ hin,
    const int* __restrict__ offsets, const unsigned short* __restrict__ csr_src,
    unsigned short* __restrict__ agg) {
    const int w = threadIdx.x >> 6, lane = threadIdx.x & 63;
    const int half = lane >> 5, hl = lane & 31;
    const int n = blockIdx.x * 4 + w;          // grid = N/4 exactly
    const int beg = offsets[n], end = offsets[n + 1];

    float accx = 0.f, accy = 0.f;
    for (int base = beg; base < end; base += 64) {
        int cnt = min(64, end - base);
        int s = (base + lane < end) ? (int)csr_src[base + lane] : 0;
        for (int kb = 0; kb < 64; kb += 16) {  // 16 edges (8 dual loads) per round
            if (kb >= cnt) break;
            unsigned u[8];
#pragma unroll
            for (int p = 0; p < 8; ++p) {
                int e = kb + 2 * p + half;
                int r = __shfl(s, e);
                u[p] = (e < cnt) ? *((const unsigned*)(hin + (size_t)r * 64) + hl) : 0u;
            }
#pragma unroll
            for (int p = 0; p < 8; ++p) {
                accx += __uint_as_float(u[p] << 16);
                accy += __uint_as_float(u[p] & 0xffff0000u);
            }
        }
    }
    float ox = accx + __shfl(accx, lane ^ 32);
    float oy = accy + __shfl(accy, lane ^ 32);
    if (half == 0)
        *((unsigned*)(agg + (size_t)n * 64) + hl) = pack_bf16x2(ox, oy);
}

// ---------------- Linear: streaming MFMA ----------------

template <int RELU>
__global__ __launch_bounds__(256) void linear_kernel(
    const unsigned short* __restrict__ agg,
    const unsigned short* __restrict__ hin,
    const float* __restrict__ Wrel, const float* __restrict__ bias,
    const float* __restrict__ Wroot, unsigned short* __restrict__ hout) {
    __shared__ unsigned short outT[4][16][72];

    const int tid = threadIdx.x;
    const int w = tid >> 6, lane = tid & 63;
    const int q = lane >> 4, c = lane & 15;
    const int g0 = (blockIdx.x * 4 + w) * 16;
    if (g0 >= N_NODES) return;

    // weight B-fragments: B[k][o], o = t*16+c, k = s*32+q*8+j
    short8 brel[4][2], broot[4][2];
    float biasv[4];
#pragma unroll
    for (int t = 0; t < 4; ++t) {
        int o = t * 16 + c;
        biasv[t] = bias[o];
#pragma unroll
        for (int s = 0; s < 2; ++s) {
            const float4* pr = (const float4*)(Wrel  + o * 64 + s * 32 + q * 8);
            const float4* po = (const float4*)(Wroot + o * 64 + s * 32 + q * 8);
            float4 r0 = pr[0], r1 = pr[1], z0 = po[0], z1 = po[1];
            short8 rr, zz;
            rr[0] = (short)bf16rne(r0.x); rr[1] = (short)bf16rne(r0.y);
            rr[2] = (short)bf16rne(r0.z); rr[3] = (short)bf16rne(r0.w);
            rr[4] = (short)bf16rne(r1.x); rr[5] = (short)bf16rne(r1.y);
            rr[6] = (short)bf16rne(r1.z); rr[7] = (short)bf16rne(r1.w);
            zz[0] = (short)bf16rne(z0.x); zz[1] = (short)bf16rne(z0.y);
            zz[2] = (short)bf16rne(z0.z); zz[3] = (short)bf16rne(z0.w);
            zz[4] = (short)bf16rne(z1.x); zz[5] = (short)bf16rne(z1.y);
            zz[6] = (short)bf16rne(z1.z); zz[7] = (short)bf16rne(z1.w);
            brel[t][s] = rr; broot[t][s] = zz;
        }
    }

    // A fragments straight from global: A[m=c][k=s*32+q*8+j]
    const int na = min(g0 + c, N_NODES - 1);
    short8 a_agg[2], a_x[2];
#pragma unroll
    for (int s = 0; s < 2; ++s) {
        a_agg[s] = *(const short8*)(agg + (size_t)na * 64 + s * 32 + q * 8);
        a_x[s]   = *(const short8*)(hin + (size_t)na * 64 + s * 32 + q * 8);
    }

    f32x4 acc4[4];
#pragma unroll
    for (int t = 0; t < 4; ++t) {
        f32x4 a0 = {biasv[t], biasv[t], biasv[t], biasv[t]};
        a0 = __builtin_amdgcn_mfma_f32_16x16x32_bf16(a_agg[0], brel[t][0], a0, 0, 0, 0);
        a0 = __builtin_amdgcn_mfma_f32_16x16x32_bf16(a_agg[1], brel[t][1], a0, 0, 0, 0);
        a0 = __builtin_amdgcn_mfma_f32_16x16x32_bf16(a_x[0],  broot[t][0], a0, 0, 0, 0);
        a0 = __builtin_amdgcn_mfma_f32_16x16x32_bf16(a_x[1],  broot[t][1], a0, 0, 0, 0);
        acc4[t] = a0;
    }

    // ReLU + bf16 + per-wave LDS transpose (C/D: col=lane&15, row=q*4+reg)
#pragma unroll
    for (int t = 0; t < 4; ++t)
#pragma unroll
        for (int r = 0; r < 4; ++r) {
            float v = acc4[t][r];
            if (RELU) v = fmaxf(v, 0.f);
            outT[w][q * 4 + r][t * 16 + c] = (unsigned short)bf16rne(v);
        }
    // same-wave LDS RAW: compiler emits lgkmcnt wait; no barrier needed

#pragma unroll
    for (int it = 0; it < 2; ++it) {
        int row = it * 8 + (lane >> 3);
        int ch = (lane & 7) * 8;
        int n = g0 + row;
        if (n < N_NODES) {
            short8 v = *(const short8*)&outT[w][row][ch];
            *(short8*)(hout + (size_t)n * 64 + ch) = v;
        }
    }
}

// ---------------- Pooling: segmented (batch is sorted), bf16 input -------

__global__ __launch_bounds__(256) void pool_kernel(
    const unsigned short* __restrict__ h, const int* __restrict__ batch,
    float* __restrict__ sums, int* __restrict__ cnt) {
    int tid = threadIdx.x;
    int w = tid >> 6, lane = tid & 63;
    int n0 = blockIdx.x * 128 + w * 32;
    if (n0 >= N_NODES) return;
    int nend = min(n0 + 32, N_NODES);
    int cur = batch[n0];
    float acc = 0.f;
    int run = 0;
    for (int n = n0; n < nend; ++n) {
        int g = batch[n];                 // wave-uniform load
        if (g != cur) {
            atomicAdd(&sums[cur * 64 + lane], acc);
            if (lane == 0) atomicAdd(&cnt[cur], run);
            acc = 0.f; run = 0; cur = g;
        }
        unsigned u = h[(size_t)n * 64 + lane];
        acc += __uint_as_float(u << 16);
        run++;
    }
    atomicAdd(&sums[cur * 64 + lane], acc);
    if (lane == 0) atomicAdd(&cnt[cur], run);
}

__global__ void final_kernel(const float* __restrict__ sums, const int* __restrict__ cnt,
                             const float* __restrict__ Wlin, const float* __restrict__ blin,
                             float* __restrict__ out) {
    __shared__ float pl[64];
    int g = blockIdx.x, lane = threadIdx.x;
    float cdiv = fmaxf((float)cnt[g], 1.0f);
    float p = sums[g * 64 + lane] / cdiv;
    out[g * 64 + lane] = p;               // pooled output
    pl[lane] = p;
    __syncthreads();
    if (lane < N_CLASSES) {
        float o = blin[lane];
#pragma unroll
        for (int k = 0; k < 64; ++k) o += pl[k] * Wlin[lane * 64 + k];
        out[N_GRAPHS * 64 + g * N_CLASSES + lane] = o;  // classifier output
    }
}

// ---------------- Launch ----------------

extern "C" void kernel_launch(void* const* d_in, const int* in_sizes, int n_in,
                              void* d_out, int out_size, void* d_ws, size_t ws_size,
                              hipStream_t stream) {
    const float* x     = (const float*)d_in[0];
    const int*   ei    = (const int*)d_in[1];
    const int*   batch = (const int*)d_in[2];
    const float* W1r = (const float*)d_in[3];
    const float* b1  = (const float*)d_in[4];
    const float* W1o = (const float*)d_in[5];
    const float* W2r = (const float*)d_in[6];
    const float* b2  = (const float*)d_in[7];
    const float* W2o = (const float*)d_in[8];
    const float* W3r = (const float*)d_in[9];
    const float* b3  = (const float*)d_in[10];
    const float* W3o = (const float*)d_in[11];
    const float* Wl  = (const float*)d_in[12];
    const float* bl  = (const float*)d_in[13];
    float* out = (float*)d_out;

    const int E = in_sizes[1] / 2;
    const int* src = ei;
    const int* dst = ei + E;

    char* p = (char*)d_ws;
    unsigned short* xb  = (unsigned short*)p; p += (size_t)N_NODES * 64 * 2;
    unsigned short* h1  = (unsigned short*)p; p += (size_t)N_NODES * 64 * 2;
    unsigned short* h2  = (unsigned short*)p; p += (size_t)N_NODES * 64 * 2;
    unsigned short* agg = (unsigned short*)p; p += (size_t)N_NODES * 64 * 2;
    unsigned short* h3  = h1;                  // layer-3 output reuses h1
    unsigned* packed    = (unsigned*)p; p += (size_t)NP * PCAP * 4;
    unsigned short* csr = (unsigned short*)p; p += (size_t)E * 2;
    int* offsets   = (int*)p;   p += (size_t)(N_NODES + 1) * 4;
    int* gcursor   = (int*)p;   p += NP * 4;
    int* pbase     = (int*)p;   p += (NP + 1) * 4;
    float* sums    = (float*)p; p += (size_t)N_GRAPHS * 64 * 4;
    int* cnt       = (int*)p;   p += N_GRAPHS * 4;

    hipMemsetAsync(gcursor, 0, NP * 4, stream);
    hipMemsetAsync(sums, 0, (size_t)(N_GRAPHS * 64 + N_GRAPHS) * 4, stream);

    const int NCHUNK = (E + EPA - 1) / EPA;  // 153
    bucket_kernel<<<NCHUNK, 256, 0, stream>>>(src, dst, gcursor, packed, E);
    cvt_kernel<<<(N_NODES * 64 / 4 + 255) / 256, 256, 0, stream>>>(x, xb, N_NODES * 64 / 4);
    pscan_kernel<<<1, 256, 0, stream>>>(gcursor, pbase, offsets);
    build_kernel<<<NP, 256, 0, stream>>>(packed, pbase, offsets, csr);

    const int GB = N_NODES / 4;            // 12500 blocks, 1 wave per node
    const int LB = (N_NODES + 63) / 64;    // 782 blocks
    gather_kernel<<<GB, 256, 0, stream>>>(xb, offsets, csr, agg);
    linear_kernel<1><<<LB, 256, 0, stream>>>(agg, xb, W1r, b1, W1o, h1);
    gather_kernel<<<GB, 256, 0, stream>>>(h1, offsets, csr, agg);
    linear_kernel<1><<<LB, 256, 0, stream>>>(agg, h1, W2r, b2, W2o, h2);
    gather_kernel<<<GB, 256, 0, stream>>>(h2, offsets, csr, agg);
    linear_kernel<0><<<LB, 256, 0, stream>>>(agg, h2, W3r, b3, W3o, h3);

    pool_kernel<<<(N_NODES + 127) / 128, 256, 0, stream>>>(h3, batch, sums, cnt);
    final_kernel<<<N_GRAPHS, 64, 0, stream>>>(sums, cnt, Wl, bl, out);
}